// Round 2
// baseline (278.761 us; speedup 1.0000x reference)
//
#include <hip/hip_runtime.h>
#include <stdint.h>

#define V 128000
#define NROWS 128
#define NBINS 4096
#define NSLICE 4
#define SLICE_ELEMS (V / NSLICE)   // 32000
#define CAP 4096
#define ZCAP 1024

__device__ __forceinline__ uint32_t f2key(uint32_t b) {
    // monotone map: float bits -> orderable uint32
    return (b & 0x80000000u) ? ~b : (b | 0x80000000u);
}
__device__ __forceinline__ float key2f(uint32_t u) {
    uint32_t b = (u & 0x80000000u) ? (u & 0x7FFFFFFFu) : ~u;
    return __uint_as_float(b);
}

// ---- K1: per-row 4096-bin histogram of top 12 key bits + q==0 zero scan ----
__global__ __launch_bounds__(256) void k_hist(const float* __restrict__ logits,
                                              const float* __restrict__ q,
                                              uint32_t* __restrict__ ghist,
                                              uint32_t* __restrict__ zcnt,
                                              unsigned long long* __restrict__ zlist) {
    __shared__ uint32_t lh[NBINS];
    const int row = blockIdx.x / NSLICE;
    const int slice = blockIdx.x % NSLICE;
    for (int i = threadIdx.x; i < NBINS; i += 256) lh[i] = 0;
    __syncthreads();
    const float4* base = (const float4*)(logits + (size_t)row * V + (size_t)slice * SLICE_ELEMS);
    const int n4 = SLICE_ELEMS / 4;   // 8000
    for (int i = threadIdx.x; i < n4; i += 256) {
        float4 v = base[i];
        atomicAdd(&lh[f2key(__float_as_uint(v.x)) >> 20], 1u);
        atomicAdd(&lh[f2key(__float_as_uint(v.y)) >> 20], 1u);
        atomicAdd(&lh[f2key(__float_as_uint(v.z)) >> 20], 1u);
        atomicAdd(&lh[f2key(__float_as_uint(v.w)) >> 20], 1u);
    }
    // q == 0 exact-zero scan (reference: probs/q = 0/0 = NaN at masked pos,
    // np.argmax returns first NaN index -> must be detected)
    const float4* qb = (const float4*)(q + (size_t)row * V + (size_t)slice * SLICE_ELEMS);
    for (int i = threadIdx.x; i < n4; i += 256) {
        float4 v = qb[i];
        const int bidx = slice * SLICE_ELEMS + i * 4;
        if (v.x == 0.f) { unsigned p0 = atomicAdd(zcnt, 1u); if (p0 < ZCAP) zlist[p0] = ((unsigned long long)row << 32) | (unsigned)(bidx + 0); }
        if (v.y == 0.f) { unsigned p0 = atomicAdd(zcnt, 1u); if (p0 < ZCAP) zlist[p0] = ((unsigned long long)row << 32) | (unsigned)(bidx + 1); }
        if (v.z == 0.f) { unsigned p0 = atomicAdd(zcnt, 1u); if (p0 < ZCAP) zlist[p0] = ((unsigned long long)row << 32) | (unsigned)(bidx + 2); }
        if (v.w == 0.f) { unsigned p0 = atomicAdd(zcnt, 1u); if (p0 < ZCAP) zlist[p0] = ((unsigned long long)row << 32) | (unsigned)(bidx + 3); }
    }
    __syncthreads();
    uint32_t* gh = ghist + (size_t)row * NBINS;
    for (int i = threadIdx.x; i < NBINS; i += 256) {
        uint32_t c = lh[i];
        if (c) atomicAdd(&gh[i], c);
    }
}

// ---------------- K2: find bin threshold b s.t. count(bin>=b) >= k -----------
__global__ __launch_bounds__(256) void k_thr(const uint32_t* __restrict__ ghist,
                                             const int* __restrict__ kk,
                                             uint32_t* __restrict__ binthr) {
    const int row = blockIdx.x;
    __shared__ uint32_t csum[256];
    const uint32_t* gh = ghist + (size_t)row * NBINS;
    const int t = threadIdx.x;
    uint32_t s = 0;
#pragma unroll
    for (int j = 0; j < 16; ++j) s += gh[t * 16 + j];
    csum[t] = s;
    __syncthreads();
    if (t == 0) {
        uint32_t krow = (uint32_t)max(kk[row], 1);
        uint32_t acc = 0;
        int chunk = 255;
        for (; chunk > 0; --chunk) {
            if (acc + csum[chunk] >= krow) break;
            acc += csum[chunk];
        }
        int bin = chunk * 16 + 15;
        for (; bin > chunk * 16; --bin) {
            acc += gh[bin];
            if (acc >= krow) break;
        }
        binthr[row] = (uint32_t)bin;
    }
}

// ---------------- K3: gather (key,idx) of all elements with bin >= b ---------
__global__ __launch_bounds__(256) void k_gather(const float* __restrict__ logits,
                                                const uint32_t* __restrict__ binthr,
                                                uint32_t* __restrict__ cnt,
                                                unsigned long long* __restrict__ list) {
    const int row = blockIdx.x / NSLICE;
    const int slice = blockIdx.x % NSLICE;
    const uint32_t b = binthr[row];
    const float4* base = (const float4*)(logits + (size_t)row * V + (size_t)slice * SLICE_ELEMS);
    const int n4 = SLICE_ELEMS / 4;
    const int lane = threadIdx.x & 63;
    unsigned long long* lrow = list + (size_t)row * CAP;
    for (int i = threadIdx.x; i < n4; i += 256) {
        float4 v = base[i];
        uint32_t u[4] = { f2key(__float_as_uint(v.x)), f2key(__float_as_uint(v.y)),
                          f2key(__float_as_uint(v.z)), f2key(__float_as_uint(v.w)) };
        const int bidx = slice * SLICE_ELEMS + i * 4;
#pragma unroll
        for (int j = 0; j < 4; ++j) {
            bool pred = (u[j] >> 20) >= b;
            unsigned long long mk = __ballot(pred);
            if (mk) {
                int leader = __ffsll((unsigned long long)mk) - 1;
                unsigned pos0 = 0;
                if (lane == leader) pos0 = atomicAdd(&cnt[row], (unsigned)__popcll(mk));
                pos0 = __shfl(pos0, leader);
                if (pred) {
                    unsigned pos = pos0 + (unsigned)__popcll(mk & ((1ull << lane) - 1ull));
                    if (pos < CAP)
                        lrow[pos] = ((unsigned long long)u[j] << 32) | (unsigned)(bidx + j);
                }
            }
        }
    }
}

// ---------------- K4: per-row sort + thresholds + exponential-race argmax ----
__global__ __launch_bounds__(1024) void k_final(const unsigned long long* __restrict__ list,
                                                const uint32_t* __restrict__ cnt,
                                                const int* __restrict__ kk,
                                                const float* __restrict__ pp,
                                                const float* __restrict__ q,
                                                const float* __restrict__ logits,
                                                const unsigned long long* __restrict__ zlist,
                                                const uint32_t* __restrict__ zcnt,
                                                int* __restrict__ out) {
    __shared__ unsigned long long keys[CAP];
    __shared__ float wtot[16], woff[16];
    __shared__ float wr[16];
    __shared__ int wi[16];
    __shared__ float sZ1, sZ2;
    __shared__ int snkeep, sJ;

    const int row = blockIdx.x;
    const int t = threadIdx.x;
    const int lane = t & 63;
    const int wave = t >> 6;

    int n_c = (int)min(cnt[row], (uint32_t)CAP);
    if (n_c <= 0) { if (t == 0) out[row] = 0; return; }
    int N2 = 1; while (N2 < n_c) N2 <<= 1;
    if (N2 < 2) N2 = 2;
    const unsigned long long* lrow = list + (size_t)row * CAP;
    for (int i = t; i < N2; i += 1024) keys[i] = (i < n_c) ? lrow[i] : 0ull;
    __syncthreads();

    // bitonic sort, DESCENDING by (key, idx)  (ties: larger idx first = "above")
    for (int ksz = 2; ksz <= N2; ksz <<= 1) {
        for (int j = ksz >> 1; j > 0; j >>= 1) {
            for (int i = t; i < N2; i += 1024) {
                int ixj = i ^ j;
                if (ixj > i) {
                    unsigned long long a = keys[i], c = keys[ixj];
                    bool up = ((i & ksz) == 0);
                    bool sw = up ? (a < c) : (a > c);
                    if (sw) { keys[i] = c; keys[ixj] = a; }
                }
            }
            __syncthreads();
        }
    }

    int krow = kk[row]; krow = max(krow, 1); krow = min(krow, n_c);
    const uint32_t Tkey = (uint32_t)(keys[krow - 1] >> 32);
    if (t == 0) {
        // first index with value < Tkey (sorted descending) == n_keep
        int lo = krow, hi = n_c;
        while (lo < hi) {
            int mid = (lo + hi) >> 1;
            if ((uint32_t)(keys[mid] >> 32) >= Tkey) lo = mid + 1; else hi = mid;
        }
        snkeep = lo;
        sJ = 0;
    }
    __syncthreads();
    const int n_keep = snkeep;
    const float m = key2f((uint32_t)(keys[0] >> 32));

    // blocked exp: thread t owns elements 4t..4t+3
    float le[4], lp[4];
    float run = 0.f;
    const int ibase = t * 4;
#pragma unroll
    for (int j2 = 0; j2 < 4; ++j2) {
        int i = ibase + j2;
        float val = 0.f;
        if (i < n_keep) val = expf(key2f((uint32_t)(keys[i] >> 32)) - m);
        le[j2] = val;
        lp[j2] = run; run += val;
    }
    // wave inclusive scan of per-thread totals
    float incl = run;
#pragma unroll
    for (int d = 1; d < 64; d <<= 1) {
        float o = __shfl_up(incl, d);
        if (lane >= d) incl += o;
    }
    if (lane == 63) wtot[wave] = incl;
    __syncthreads();
    if (t == 0) {
        float acc = 0.f;
        for (int w = 0; w < 16; ++w) { woff[w] = acc; acc += wtot[w]; }
        sZ1 = acc;
    }
    __syncthreads();
    const float Z1 = sZ1;
    const float thr = pp[row] * Z1;          // keep i iff exclusive_prefix(i) < p*Z1
    const float texcl = woff[wave] + (incl - run);
    int c = 0;
#pragma unroll
    for (int j2 = 0; j2 < 4; ++j2) {
        int i = ibase + j2;
        if (i < n_keep && (texcl + lp[j2]) < thr) c++;
    }
#pragma unroll
    for (int d = 1; d < 64; d <<= 1) c += __shfl_xor(c, d);
    if (lane == 0) atomicAdd(&sJ, c);
    __syncthreads();
    const int J = sJ;
    if (t == 0) sZ2 = Z1;
    __syncthreads();
    if (J < n_keep) {
#pragma unroll
        for (int j2 = 0; j2 < 4; ++j2) {
            int i = ibase + j2;
            if (i == J) sZ2 = texcl + lp[j2];
        }
    }
    __syncthreads();
    const float Z2 = sZ2;

    // exponential-race argmax over kept prefix [0, J)
    float br = -1.f; int bi = 0x7fffffff;
#pragma unroll
    for (int j2 = 0; j2 < 4; ++j2) {
        int i = ibase + j2;
        if (i < J) {
            int idx = (int)(keys[i] & 0xffffffffu);
            float qv = q[(size_t)row * V + idx];
            float r = (le[j2] / Z2) / qv;
            if (r > br || (r == br && idx < bi)) { br = r; bi = idx; }
        }
    }
#pragma unroll
    for (int d = 1; d < 64; d <<= 1) {
        float orr = __shfl_xor(br, d);
        int oi = __shfl_xor(bi, d);
        if (orr > br || (orr == br && oi < bi)) { br = orr; bi = oi; }
    }
    if (lane == 0) { wr[wave] = br; wi[wave] = bi; }
    __syncthreads();
    if (t == 0) {
        float bb = wr[0]; int bbi = wi[0];
        for (int w = 1; w < 16; ++w) {
            if (wr[w] > bb || (wr[w] == bb && wi[w] < bbi)) { bb = wr[w]; bbi = wi[w]; }
        }
        // NaN override: q==0 at a MASKED position -> probs/q = 0/0 = NaN;
        // np.argmax returns the first NaN index (NaN beats inf and finite).
        // Kept set is exactly the first J entries of the descending (val,idx)
        // order, so membership test is key64 >= keys[J-1].
        int nanidx = 0x7fffffff;
        int nz = (int)min(*zcnt, (uint32_t)ZCAP);
        unsigned long long lastkept = keys[J - 1];
        for (int e = 0; e < nz; ++e) {
            unsigned long long ent = zlist[e];
            if ((int)(ent >> 32) != row) continue;
            int zi = (int)(ent & 0xffffffffu);
            uint32_t kb = f2key(__float_as_uint(logits[(size_t)row * V + zi]));
            unsigned long long key64 = ((unsigned long long)kb << 32) | (unsigned)zi;
            if (key64 < lastkept) nanidx = min(nanidx, zi);   // masked -> NaN
        }
        out[row] = (nanidx != 0x7fffffff) ? nanidx : bbi;
    }
}

extern "C" void kernel_launch(void* const* d_in, const int* in_sizes, int n_in,
                              void* d_out, int out_size, void* d_ws, size_t ws_size,
                              hipStream_t stream) {
    const float* logits = (const float*)d_in[0];
    const int* kk       = (const int*)d_in[1];
    const float* pp     = (const float*)d_in[2];
    const float* q      = (const float*)d_in[3];
    int* out            = (int*)d_out;

    char* ws = (char*)d_ws;
    const size_t HIST_B = (size_t)NROWS * NBINS * 4;                 // 2 MB
    uint32_t* ghist  = (uint32_t*)ws;
    uint32_t* binthr = (uint32_t*)(ws + HIST_B);                     // 512 B
    uint32_t* cnt    = (uint32_t*)(ws + HIST_B + 1024);              // 512 B
    uint32_t* zcnt   = (uint32_t*)(ws + HIST_B + 1536);              // 4 B
    unsigned long long* list  = (unsigned long long*)(ws + HIST_B + 8192);          // 4 MB
    unsigned long long* zlist = (unsigned long long*)(ws + HIST_B + 8192
                                   + (size_t)NROWS * CAP * 8);                      // 8 KB

    // zero histogram + counters every call (graph-replay safe)
    hipMemsetAsync(d_ws, 0, HIST_B + 4096, stream);

    hipLaunchKernelGGL(k_hist,   dim3(NROWS * NSLICE), dim3(256),  0, stream,
                       logits, q, ghist, zcnt, zlist);
    hipLaunchKernelGGL(k_thr,    dim3(NROWS),          dim3(256),  0, stream, ghist, kk, binthr);
    hipLaunchKernelGGL(k_gather, dim3(NROWS * NSLICE), dim3(256),  0, stream, logits, binthr, cnt, list);
    hipLaunchKernelGGL(k_final,  dim3(NROWS),          dim3(1024), 0, stream,
                       list, cnt, kk, pp, q, logits, zlist, zcnt, out);
}

// Round 3
// 96.319 us; speedup vs baseline: 2.8942x; 2.8942x over previous
//
#include <hip/hip_runtime.h>
#include <stdint.h>

#define V 128000
#define NROWS 128
#define NBINS 4096
#define NSH 4                 // hist slices per row
#define SH_ELEMS (V / NSH)    // 32000
#define NSG 8                 // gather slices per row
#define SG_ELEMS (V / NSG)    // 16000
#define SCAP 1024             // per-slice candidate capacity
#define CAPK 8192             // max total candidates per row (8*1024)
#define ZCAP 1024

typedef unsigned long long ull;

__device__ __forceinline__ uint32_t f2key(uint32_t b) {
    // monotone map: float bits -> orderable uint32
    return (b & 0x80000000u) ? ~b : (b | 0x80000000u);
}
__device__ __forceinline__ float key2f(uint32_t u) {
    uint32_t b = (u & 0x80000000u) ? (u & 0x7FFFFFFFu) : ~u;
    return __uint_as_float(b);
}

// ---- K1: per-row 4096-bin histogram of top 12 key bits + q==0 zero scan ----
__global__ __launch_bounds__(256) void k_hist(const float* __restrict__ logits,
                                              const float* __restrict__ q,
                                              uint32_t* __restrict__ ghist,
                                              uint32_t* __restrict__ zcnt,
                                              ull* __restrict__ zlist) {
    __shared__ uint32_t lh[NBINS];
    const int row = blockIdx.x / NSH;
    const int slice = blockIdx.x % NSH;
    for (int i = threadIdx.x; i < NBINS; i += 256) lh[i] = 0;
    __syncthreads();
    const float4* base = (const float4*)(logits + (size_t)row * V + (size_t)slice * SH_ELEMS);
    const int n4 = SH_ELEMS / 4;   // 8000
    for (int i = threadIdx.x; i < n4; i += 256) {
        float4 v = base[i];
        atomicAdd(&lh[f2key(__float_as_uint(v.x)) >> 20], 1u);
        atomicAdd(&lh[f2key(__float_as_uint(v.y)) >> 20], 1u);
        atomicAdd(&lh[f2key(__float_as_uint(v.z)) >> 20], 1u);
        atomicAdd(&lh[f2key(__float_as_uint(v.w)) >> 20], 1u);
    }
    // q == 0 exact-zero scan (reference: probs/q = 0/0 = NaN at masked pos;
    // np.argmax returns first NaN index). ~2 hits expected globally.
    const float4* qb = (const float4*)(q + (size_t)row * V + (size_t)slice * SH_ELEMS);
    for (int i = threadIdx.x; i < n4; i += 256) {
        float4 v = qb[i];
        const int bidx = slice * SH_ELEMS + i * 4;
        if (v.x == 0.f) { unsigned p0 = atomicAdd(zcnt, 1u); if (p0 < ZCAP) zlist[p0] = ((ull)row << 32) | (unsigned)(bidx + 0); }
        if (v.y == 0.f) { unsigned p0 = atomicAdd(zcnt, 1u); if (p0 < ZCAP) zlist[p0] = ((ull)row << 32) | (unsigned)(bidx + 1); }
        if (v.z == 0.f) { unsigned p0 = atomicAdd(zcnt, 1u); if (p0 < ZCAP) zlist[p0] = ((ull)row << 32) | (unsigned)(bidx + 2); }
        if (v.w == 0.f) { unsigned p0 = atomicAdd(zcnt, 1u); if (p0 < ZCAP) zlist[p0] = ((ull)row << 32) | (unsigned)(bidx + 3); }
    }
    __syncthreads();
    uint32_t* gh = ghist + (size_t)row * NBINS;
    for (int i = threadIdx.x; i < NBINS; i += 256) {
        uint32_t c = lh[i];
        if (c) atomicAdd(&gh[i], c);
    }
}

// ---------------- K2: find bin threshold b s.t. count(bin>=b) >= k -----------
__global__ __launch_bounds__(256) void k_thr(const uint32_t* __restrict__ ghist,
                                             const int* __restrict__ kk,
                                             uint32_t* __restrict__ binthr) {
    const int row = blockIdx.x;
    __shared__ uint32_t csum[256];
    const uint32_t* gh = ghist + (size_t)row * NBINS;
    const int t = threadIdx.x;
    uint32_t s = 0;
#pragma unroll
    for (int j = 0; j < 16; ++j) s += gh[t * 16 + j];
    csum[t] = s;
    __syncthreads();
    if (t == 0) {
        uint32_t krow = (uint32_t)max(kk[row], 1);
        uint32_t acc = 0;
        int chunk = 255;
        for (; chunk > 0; --chunk) {
            if (acc + csum[chunk] >= krow) break;
            acc += csum[chunk];
        }
        int bin = chunk * 16 + 15;
        for (; bin > chunk * 16; --bin) {
            acc += gh[bin];
            if (acc >= krow) break;
        }
        binthr[row] = (uint32_t)bin;
    }
}

// ---- K3: gather candidates into slice-PRIVATE segments (no global atomics) --
__global__ __launch_bounds__(256) void k_gather(const float* __restrict__ logits,
                                                const uint32_t* __restrict__ binthr,
                                                uint32_t* __restrict__ scnt,
                                                ull* __restrict__ list) {
    __shared__ ull lbuf[SCAP];
    __shared__ uint32_t lcnt;
    const int row = blockIdx.x / NSG;
    const int slice = blockIdx.x % NSG;
    if (threadIdx.x == 0) lcnt = 0;
    __syncthreads();
    const uint32_t b = binthr[row];
    const float4* base = (const float4*)(logits + (size_t)row * V + (size_t)slice * SG_ELEMS);
    const int n4 = SG_ELEMS / 4;  // 4000
    for (int i = threadIdx.x; i < n4; i += 256) {
        float4 v = base[i];
        uint32_t u[4] = { f2key(__float_as_uint(v.x)), f2key(__float_as_uint(v.y)),
                          f2key(__float_as_uint(v.z)), f2key(__float_as_uint(v.w)) };
        const int bidx = slice * SG_ELEMS + i * 4;
#pragma unroll
        for (int j = 0; j < 4; ++j) {
            if ((u[j] >> 20) >= b) {
                unsigned pos = atomicAdd(&lcnt, 1u);     // LDS atomic: cheap
                if (pos < SCAP)
                    lbuf[pos] = ((ull)u[j] << 32) | (unsigned)(bidx + j);
            }
        }
    }
    __syncthreads();
    uint32_t c = min(lcnt, (uint32_t)SCAP);
    ull* seg = list + (size_t)(row * NSG + slice) * SCAP;
    for (int i = threadIdx.x; i < (int)c; i += 256) seg[i] = lbuf[i];
    if (threadIdx.x == 0) scnt[row * NSG + slice] = c;
}

// ---------------- K4: per-row sort + thresholds + exponential-race argmax ----
__global__ __launch_bounds__(1024) void k_final(const ull* __restrict__ list,
                                                const uint32_t* __restrict__ scnt,
                                                const int* __restrict__ kk,
                                                const float* __restrict__ pp,
                                                const float* __restrict__ q,
                                                const float* __restrict__ logits,
                                                const ull* __restrict__ zlist,
                                                const uint32_t* __restrict__ zcnt,
                                                int* __restrict__ out) {
    __shared__ ull keys[CAPK];
    __shared__ int soff[NSG + 1];
    __shared__ float wtot[16], woff[16];
    __shared__ float wr[16];
    __shared__ int wi[16];
    __shared__ float sZ1, sZ2;
    __shared__ int snkeep, sJ;

    const int row = blockIdx.x;
    const int t = threadIdx.x;
    const int lane = t & 63;
    const int wave = t >> 6;

    if (t == 0) {
        int acc = 0;
        for (int s2 = 0; s2 < NSG; ++s2) {
            soff[s2] = acc;
            acc += (int)min(scnt[row * NSG + s2], (uint32_t)SCAP);
        }
        soff[NSG] = acc;
    }
    __syncthreads();
    const int n_c = soff[NSG];
    if (n_c <= 0) { if (t == 0) out[row] = 0; return; }
    int N2 = 1; while (N2 < n_c) N2 <<= 1;
    if (N2 < 2) N2 = 2;

    // concatenate the 8 segments
    for (int s2 = 0; s2 < NSG; ++s2) {
        const int c0 = soff[s2], c1 = soff[s2 + 1];
        const ull* seg = list + (size_t)(row * NSG + s2) * SCAP;
        for (int i = c0 + t; i < c1; i += 1024) keys[i] = seg[i - c0];
    }
    for (int i = t; i < N2; i += 1024) if (i >= n_c) keys[i] = 0ull;
    __syncthreads();

    // bitonic sort, DESCENDING by (key, idx); zero-padding sorts to the end
    for (int ksz = 2; ksz <= N2; ksz <<= 1) {
        for (int j = ksz >> 1; j > 0; j >>= 1) {
            for (int i = t; i < N2; i += 1024) {
                int ixj = i ^ j;
                if (ixj > i) {
                    ull a = keys[i], c = keys[ixj];
                    bool up = ((i & ksz) == 0);
                    bool sw = up ? (a < c) : (a > c);
                    if (sw) { keys[i] = c; keys[ixj] = a; }
                }
            }
            __syncthreads();
        }
    }

    int krow = kk[row]; krow = max(krow, 1); krow = min(krow, n_c);
    const uint32_t Tkey = (uint32_t)(keys[krow - 1] >> 32);
    if (t == 0) {
        // first index with value < Tkey (sorted descending) == n_keep
        int lo = krow, hi = n_c;
        while (lo < hi) {
            int mid = (lo + hi) >> 1;
            if ((uint32_t)(keys[mid] >> 32) >= Tkey) lo = mid + 1; else hi = mid;
        }
        snkeep = lo;
        sJ = 0;
    }
    __syncthreads();
    const int n_keep = snkeep;    // <= ~k+ties << 4096, so EPT=4 region covers it
    const float m = key2f((uint32_t)(keys[0] >> 32));

    // blocked exp: thread t owns elements 4t..4t+3 (identical grouping to the
    // verified round-2 kernel -> bit-identical Z1/J/Z2 on same candidate set)
    float le[4], lp[4];
    float run = 0.f;
    const int ibase = t * 4;
#pragma unroll
    for (int j2 = 0; j2 < 4; ++j2) {
        int i = ibase + j2;
        float val = 0.f;
        if (i < n_keep) val = expf(key2f((uint32_t)(keys[i] >> 32)) - m);
        le[j2] = val;
        lp[j2] = run; run += val;
    }
    // wave inclusive scan of per-thread totals
    float incl = run;
#pragma unroll
    for (int d = 1; d < 64; d <<= 1) {
        float o = __shfl_up(incl, d);
        if (lane >= d) incl += o;
    }
    if (lane == 63) wtot[wave] = incl;
    __syncthreads();
    if (t == 0) {
        float acc = 0.f;
        for (int w = 0; w < 16; ++w) { woff[w] = acc; acc += wtot[w]; }
        sZ1 = acc;
    }
    __syncthreads();
    const float Z1 = sZ1;
    const float thr = pp[row] * Z1;          // keep i iff exclusive_prefix(i) < p*Z1
    const float texcl = woff[wave] + (incl - run);
    int c = 0;
#pragma unroll
    for (int j2 = 0; j2 < 4; ++j2) {
        int i = ibase + j2;
        if (i < n_keep && (texcl + lp[j2]) < thr) c++;
    }
#pragma unroll
    for (int d = 1; d < 64; d <<= 1) c += __shfl_xor(c, d);
    if (lane == 0) atomicAdd(&sJ, c);
    __syncthreads();
    const int J = sJ;
    if (t == 0) sZ2 = Z1;
    __syncthreads();
    if (J < n_keep) {
#pragma unroll
        for (int j2 = 0; j2 < 4; ++j2) {
            int i = ibase + j2;
            if (i == J) sZ2 = texcl + lp[j2];
        }
    }
    __syncthreads();
    const float Z2 = sZ2;

    // exponential-race argmax over kept prefix [0, J)
    float br = -1.f; int bi = 0x7fffffff;
#pragma unroll
    for (int j2 = 0; j2 < 4; ++j2) {
        int i = ibase + j2;
        if (i < J) {
            int idx = (int)(keys[i] & 0xffffffffu);
            float qv = q[(size_t)row * V + idx];
            float r = (le[j2] / Z2) / qv;
            if (r > br || (r == br && idx < bi)) { br = r; bi = idx; }
        }
    }
#pragma unroll
    for (int d = 1; d < 64; d <<= 1) {
        float orr = __shfl_xor(br, d);
        int oi = __shfl_xor(bi, d);
        if (orr > br || (orr == br && oi < bi)) { br = orr; bi = oi; }
    }
    if (lane == 0) { wr[wave] = br; wi[wave] = bi; }
    __syncthreads();
    if (t == 0) {
        float bb = wr[0]; int bbi = wi[0];
        for (int w = 1; w < 16; ++w) {
            if (wr[w] > bb || (wr[w] == bb && wi[w] < bbi)) { bb = wr[w]; bbi = wi[w]; }
        }
        // NaN override: q==0 at a MASKED position -> probs/q = 0/0 = NaN;
        // np.argmax returns the first NaN index (NaN beats inf and finite).
        // Kept set is exactly the first J entries of the descending (val,idx)
        // order, so membership test is key64 >= keys[J-1].
        int nanidx = 0x7fffffff;
        int nz = (int)min(*zcnt, (uint32_t)ZCAP);
        ull lastkept = keys[J - 1];
        for (int e = 0; e < nz; ++e) {
            ull ent = zlist[e];
            if ((int)(ent >> 32) != row) continue;
            int zi = (int)(ent & 0xffffffffu);
            uint32_t kb = f2key(__float_as_uint(logits[(size_t)row * V + zi]));
            ull key64 = ((ull)kb << 32) | (unsigned)zi;
            if (key64 < lastkept) nanidx = min(nanidx, zi);   // masked -> NaN
        }
        out[row] = (nanidx != 0x7fffffff) ? nanidx : bbi;
    }
}

extern "C" void kernel_launch(void* const* d_in, const int* in_sizes, int n_in,
                              void* d_out, int out_size, void* d_ws, size_t ws_size,
                              hipStream_t stream) {
    const float* logits = (const float*)d_in[0];
    const int* kk       = (const int*)d_in[1];
    const float* pp     = (const float*)d_in[2];
    const float* q      = (const float*)d_in[3];
    int* out            = (int*)d_out;

    char* ws = (char*)d_ws;
    const size_t HIST_B = (size_t)NROWS * NBINS * 4;                 // 2 MB
    uint32_t* ghist  = (uint32_t*)ws;
    uint32_t* binthr = (uint32_t*)(ws + HIST_B);                     // 512 B
    uint32_t* zcnt   = (uint32_t*)(ws + HIST_B + 512);               // 4 B
    uint32_t* scnt   = (uint32_t*)(ws + HIST_B + 4096);              // 4 KB
    ull* list  = (ull*)(ws + HIST_B + 16384);                        // 8 MB
    ull* zlist = (ull*)(ws + HIST_B + 16384 + (size_t)NROWS * NSG * SCAP * 8); // 8 KB

    // zero histogram + zcnt every call (graph-replay safe). binthr/scnt/list
    // are written unconditionally each call.
    hipMemsetAsync(d_ws, 0, HIST_B + 1024, stream);

    hipLaunchKernelGGL(k_hist,   dim3(NROWS * NSH), dim3(256),  0, stream,
                       logits, q, ghist, zcnt, zlist);
    hipLaunchKernelGGL(k_thr,    dim3(NROWS),       dim3(256),  0, stream, ghist, kk, binthr);
    hipLaunchKernelGGL(k_gather, dim3(NROWS * NSG), dim3(256),  0, stream,
                       logits, binthr, scnt, list);
    hipLaunchKernelGGL(k_final,  dim3(NROWS),       dim3(1024), 0, stream,
                       list, scnt, kk, pp, q, logits, zlist, zcnt, out);
}